// Round 6
// baseline (12758.102 us; speedup 1.0000x reference)
//
#include <hip/hip_runtime.h>

// 2-layer LSTM, B=64, S=2048, F=40, EMB=128, HID=256 — R6 sentinel protocol.
// Decoupled pipeline (R2-style): per group(16 batches) per layer, 4 slice-blocks
// (64 cols each, 512 thr). Producer: packed u64 payload {2 cols x hi/lo bf16},
// one store/lane -> s_waitcnt vmcnt(0) -> per-wave sentinel. Consumers spin on
// 3-7 broadcast sentinel words only, then single-shot payload fetch (no tag
// re-reads). Wave-diagonal chunk ownership (wave w <-> partner wave w).
// D=8 rings; L0 free-runs ahead of L1, throttled by a lag-5 progress probe.
// Numerics: weights bf16, A hi/lo bf16 split, c/h/gates fp32 (as R1-R5).

#define Sz 2048
#define NG 4
#define NS 4
#define RD 8

typedef __attribute__((ext_vector_type(8))) short short8;
typedef __attribute__((ext_vector_type(4))) float f32x4;

// ws offsets in u64 units
#define RING0 0                   // [g][slot8][slice4] x 512 u64
#define RING1 65536
#define SENT0 131072              // [g][slot8][slice4][wave8] u64
#define SENT1 132096

// LDS byte offsets (fragment order: (kt*4+q)*256 + m*16 + z*2)
#define H0_HI 0
#define H0_LO 8192
#define H1_HI 16384
#define H1_LO 24576
#define POUT  32768               // [2][8][16] f32
#define SMEM_BYTES 33792

__device__ __forceinline__ unsigned short bf16_rne(float f) {
  unsigned u = __float_as_uint(f);
  u += 0x7FFFu + ((u >> 16) & 1u);
  return (unsigned short)(u >> 16);
}
__device__ __forceinline__ unsigned pk_enc(float f) {
  unsigned short hb = bf16_rne(f);
  float fh = __uint_as_float((unsigned)hb << 16);
  unsigned short lb = bf16_rne(f - fh);
  return ((unsigned)hb << 16) | (unsigned)lb;
}
__device__ __forceinline__ void stage_u64(char* smem, int ph, int pl,
                                          int col0, int m, unsigned long long v) {
  const int kt = col0 >> 5, qq = (col0 >> 3) & 3, z = col0 & 7;
  const int off = (kt * 4 + qq) * 256 + m * 16 + z * 2;
  *(unsigned*)(smem + ph + off) = (unsigned)v;          // {hi(c0), hi(c1)}
  *(unsigned*)(smem + pl + off) = (unsigned)(v >> 32);  // {lo(c0), lo(c1)}
}
__device__ __forceinline__ void x_frag(const float* xf, short8& aH, short8& aL) {
  union { short8 v; unsigned short u[8]; } h, l;
#pragma unroll
  for (int z = 0; z < 8; ++z) {
    unsigned short hb = bf16_rne(xf[z]);
    h.u[z] = hb;
    l.u[z] = bf16_rne(xf[z] - __uint_as_float((unsigned)hb << 16));
  }
  aH = h.v; aL = l.v;
}

__global__ void init_out(const float* __restrict__ b_out, float* __restrict__ out) {
  int i = blockIdx.x * 512 + threadIdx.x;
  if (i < 64 * Sz) out[i] = b_out[0];
}

__global__ __launch_bounds__(512, 1) void lstm_v6(
    const float* __restrict__ xin, const float* __restrict__ W_in,
    const float* __restrict__ b_in, const float* __restrict__ W_ih0,
    const float* __restrict__ W_hh0, const float* __restrict__ b_ih0,
    const float* __restrict__ b_hh0, const float* __restrict__ W_ih1,
    const float* __restrict__ W_hh1, const float* __restrict__ b_ih1,
    const float* __restrict__ b_hh1, const float* __restrict__ W_out,
    const float* __restrict__ b_out, float* __restrict__ out,
    unsigned long long* __restrict__ ws64) {
  const int bx = blockIdx.x;
  if (bx >= 32) return;
  const int g = bx & 3;
  const int L = (bx >> 2) & 1;   // 0: layer0 chain, 1: layer1 chain
  const int s = bx >> 3;         // slice 0..3 (64 cols)
  const int tid = (int)threadIdx.x;
  const int w = tid >> 6;        // wave 0..7 (8 cols each)
  const int lane = tid & 63;
  const int q = lane >> 4, n16 = lane & 15;
  const int gidx = n16 >> 2, c4 = n16 & 3;
  const int cpo = lane >> 4, pm = lane & 15;   // payload coords

  __shared__ __align__(16) char smem[SMEM_BYTES];
  float* const pout = (float*)(smem + POUT);

  // ---------------- persistent weights ----------------
  // col(j) = s*64 + w*8 + c4*2 + j  (adjacent pair per lane)
  short8 wfA[2][8];   // L0: W_hh0 ; L1: W_ih1   (x H0-plane)
  short8 wfB[2][8];   // L0: W_comb (kt<2) ; L1: W_hh1 (x H1-plane)
  float bb[2];
  float wo2[2] = {0.f, 0.f};
  {
    const float* WA = L ? W_ih1 : W_hh0;
#pragma unroll
    for (int j = 0; j < 2; ++j) {
      const int col = s * 64 + w * 8 + c4 * 2 + j;
      const int row = gidx * 256 + col;
#pragma unroll
      for (int kt = 0; kt < 8; ++kt) {
        const float* src = WA + (size_t)row * 256 + kt * 32 + q * 8;
        union { short8 v; unsigned short u[8]; } fr;
#pragma unroll
        for (int z = 0; z < 8; ++z) fr.u[z] = bf16_rne(src[z]);
        wfA[j][kt] = fr.v;
      }
      if (L) {
#pragma unroll
        for (int kt = 0; kt < 8; ++kt) {
          const float* src = W_hh1 + (size_t)row * 256 + kt * 32 + q * 8;
          union { short8 v; unsigned short u[8]; } fr;
#pragma unroll
          for (int z = 0; z < 8; ++z) fr.u[z] = bf16_rne(src[z]);
          wfB[j][kt] = fr.v;
        }
        bb[j] = b_ih1[row] + b_hh1[row];
        wo2[j] = W_out[col];
      } else {
        float sv0[8], sv1[8];
#pragma unroll
        for (int z = 0; z < 8; ++z) { sv0[z] = 0.f; sv1[z] = 0.f; }
        float bacc = 0.f;
        const float* wr = W_ih0 + (size_t)row * 128;
        for (int e = 0; e < 128; ++e) {
          float wv = wr[e];
          const float* wiv = W_in + e * 40;
          bacc += wv * b_in[e];
#pragma unroll
          for (int z = 0; z < 8; ++z) sv0[z] += wv * wiv[q * 8 + z];
          if (q == 0) {
#pragma unroll
            for (int z = 0; z < 8; ++z) sv1[z] += wv * wiv[32 + z];
          }
        }
        union { short8 v; unsigned short u[8]; } f0, f1;
#pragma unroll
        for (int z = 0; z < 8; ++z) {
          f0.u[z] = bf16_rne(sv0[z]);
          f1.u[z] = (q == 0) ? bf16_rne(sv1[z]) : (unsigned short)0;
        }
        wfB[j][0] = f0.v; wfB[j][1] = f1.v;
        bb[j] = b_ih0[row] + b_hh0[row] + bacc;
      }
    }
  }

  // zero LDS (h(-1) = 0 planes; pout)
  for (int i = tid; i < SMEM_BYTES / 4; i += 512) ((int*)smem)[i] = 0;
  __syncthreads();

  float cst[2][4] = {{0.f, 0.f, 0.f, 0.f}, {0.f, 0.f, 0.f, 0.f}};
  const bool g0b = gidx & 1, g1b = gidx & 2;
  const float sc = (gidx == 2) ? 2.f : 1.f;

#pragma unroll 1
  for (int t = 0; t < Sz; ++t) {
    // ---- L0: x(t) loads issued early (overlap with spin) ----
    float4 xa, xb4, xc, xd;
    if (L == 0) {
      const float* xp = xin + ((size_t)(g * 16 + n16) * Sz + t) * 40;
      xa = *(const float4*)(xp + q * 8);
      xb4 = *(const float4*)(xp + q * 8 + 4);
      if (q == 0) { xc = *(const float4*)(xp + 32); xd = *(const float4*)(xp + 36); }
    }

    // ---- per-wave sentinel spin (tiny broadcast loads) ----
    {
      const unsigned long long* sa = nullptr;
      long long thr = 0; int mode = 0;  // 1: ==, 2: >=
      if (L == 0) {
        if (lane < 3 && t > 0) {
          const int ps = lane + (lane >= s);
          sa = ws64 + SENT0 + (size_t)((g * 8 + ((t - 1) & 7)) * 4 + ps) * 8 + w;
          thr = t; mode = 1;
        } else if (lane == 3 && t >= 8) {  // throttle: L1 progress probe
          sa = ws64 + SENT1 + (size_t)((g * 8 + ((t - 6) & 7)) * 4 + 0) * 8 + w;
          thr = t - 5; mode = 2;
        }
      } else {
        if (lane < 3 && t > 0) {
          const int ps = lane + (lane >= s);
          sa = ws64 + SENT1 + (size_t)((g * 8 + ((t - 1) & 7)) * 4 + ps) * 8 + w;
          thr = t; mode = 1;
        } else if (lane >= 3 && lane < 7) {
          const int pi = lane - 3;
          sa = ws64 + SENT0 + (size_t)((g * 8 + (t & 7)) * 4 + pi) * 8 + w;
          thr = t + 1; mode = 1;
        }
      }
      int fails = 0;
      for (;;) {
        bool ok = true;
        if (mode) {
          long long v = (long long)__hip_atomic_load(sa, __ATOMIC_RELAXED,
                                                     __HIP_MEMORY_SCOPE_AGENT);
          ok = (mode == 1) ? (v == thr) : (v >= thr);
        }
        if (__all(ok)) break;
        if (++fails > 24) __builtin_amdgcn_s_sleep(1);
      }
    }

    // ---- single-shot payload fetch + fragment-order staging ----
    if (L == 0) {
      if (t > 0) {
        const int slot = (t - 1) & 7;
#pragma unroll
        for (int i = 0; i < 3; ++i) {
          const int ps = i + (i >= s);
          unsigned long long v = __hip_atomic_load(
              ws64 + RING0 + (size_t)((g * 8 + slot) * 4 + ps) * 512 +
                  (w * 4 + cpo) * 16 + pm,
              __ATOMIC_RELAXED, __HIP_MEMORY_SCOPE_AGENT);
          stage_u64(smem, H0_HI, H0_LO, ps * 64 + (w * 4 + cpo) * 2, pm, v);
        }
      }
    } else {
#pragma unroll
      for (int i = 0; i < 4; ++i) {
        unsigned long long v = __hip_atomic_load(
            ws64 + RING0 + (size_t)((g * 8 + (t & 7)) * 4 + i) * 512 +
                (w * 4 + cpo) * 16 + pm,
            __ATOMIC_RELAXED, __HIP_MEMORY_SCOPE_AGENT);
        stage_u64(smem, H0_HI, H0_LO, i * 64 + (w * 4 + cpo) * 2, pm, v);
      }
      if (t > 0) {
        const int slot = (t - 1) & 7;
#pragma unroll
        for (int i = 0; i < 3; ++i) {
          const int ps = i + (i >= s);
          unsigned long long v = __hip_atomic_load(
              ws64 + RING1 + (size_t)((g * 8 + slot) * 4 + ps) * 512 +
                  (w * 4 + cpo) * 16 + pm,
              __ATOMIC_RELAXED, __HIP_MEMORY_SCOPE_AGENT);
          stage_u64(smem, H1_HI, H1_LO, ps * 64 + (w * 4 + cpo) * 2, pm, v);
        }
      }
    }
    __syncthreads();  // A: staging complete

    // pipelined out-partial flush (L1, h1(t-1))
    if (L == 1 && w == 0 && lane < 16 && t > 0) {
      const int par = (t - 1) & 1;
      float sum = 0.f;
#pragma unroll
      for (int ww = 0; ww < 8; ++ww) sum += pout[par * 128 + ww * 16 + lane];
      atomicAdd(out + (size_t)(g * 16 + lane) * Sz + (t - 1), sum);
    }

    // ---- MFMA (conflict-free fragment reads) ----
    f32x4 acc[2] = {{0.f, 0.f, 0.f, 0.f}, {0.f, 0.f, 0.f, 0.f}};
    const int lb = lane * 16;
    if (L == 0) {
      short8 axH, axL;
      {
        float xf[8] = {xa.x, xa.y, xa.z, xa.w, xb4.x, xb4.y, xb4.z, xb4.w};
        x_frag(xf, axH, axL);
      }
      acc[0] = __builtin_amdgcn_mfma_f32_16x16x32_bf16(axH, wfB[0][0], acc[0], 0, 0, 0);
      acc[0] = __builtin_amdgcn_mfma_f32_16x16x32_bf16(axL, wfB[0][0], acc[0], 0, 0, 0);
      acc[1] = __builtin_amdgcn_mfma_f32_16x16x32_bf16(axH, wfB[1][0], acc[1], 0, 0, 0);
      acc[1] = __builtin_amdgcn_mfma_f32_16x16x32_bf16(axL, wfB[1][0], acc[1], 0, 0, 0);
      {
        float xg[8] = {0, 0, 0, 0, 0, 0, 0, 0};
        if (q == 0) {
          xg[0] = xc.x; xg[1] = xc.y; xg[2] = xc.z; xg[3] = xc.w;
          xg[4] = xd.x; xg[5] = xd.y; xg[6] = xd.z; xg[7] = xd.w;
        }
        x_frag(xg, axH, axL);
      }
      acc[0] = __builtin_amdgcn_mfma_f32_16x16x32_bf16(axH, wfB[0][1], acc[0], 0, 0, 0);
      acc[0] = __builtin_amdgcn_mfma_f32_16x16x32_bf16(axL, wfB[0][1], acc[0], 0, 0, 0);
      acc[1] = __builtin_amdgcn_mfma_f32_16x16x32_bf16(axH, wfB[1][1], acc[1], 0, 0, 0);
      acc[1] = __builtin_amdgcn_mfma_f32_16x16x32_bf16(axL, wfB[1][1], acc[1], 0, 0, 0);
#pragma unroll
      for (int kt = 0; kt < 8; ++kt) {
        short8 aH = *(const short8*)(smem + H0_HI + kt * 1024 + lb);
        short8 aL = *(const short8*)(smem + H0_LO + kt * 1024 + lb);
        acc[0] = __builtin_amdgcn_mfma_f32_16x16x32_bf16(aH, wfA[0][kt], acc[0], 0, 0, 0);
        acc[0] = __builtin_amdgcn_mfma_f32_16x16x32_bf16(aL, wfA[0][kt], acc[0], 0, 0, 0);
        acc[1] = __builtin_amdgcn_mfma_f32_16x16x32_bf16(aH, wfA[1][kt], acc[1], 0, 0, 0);
        acc[1] = __builtin_amdgcn_mfma_f32_16x16x32_bf16(aL, wfA[1][kt], acc[1], 0, 0, 0);
      }
    } else {
#pragma unroll
      for (int kt = 0; kt < 8; ++kt) {
        short8 aH = *(const short8*)(smem + H0_HI + kt * 1024 + lb);
        short8 aL = *(const short8*)(smem + H0_LO + kt * 1024 + lb);
        acc[0] = __builtin_amdgcn_mfma_f32_16x16x32_bf16(aH, wfA[0][kt], acc[0], 0, 0, 0);
        acc[0] = __builtin_amdgcn_mfma_f32_16x16x32_bf16(aL, wfA[0][kt], acc[0], 0, 0, 0);
        acc[1] = __builtin_amdgcn_mfma_f32_16x16x32_bf16(aH, wfA[1][kt], acc[1], 0, 0, 0);
        acc[1] = __builtin_amdgcn_mfma_f32_16x16x32_bf16(aL, wfA[1][kt], acc[1], 0, 0, 0);
        short8 bH = *(const short8*)(smem + H1_HI + kt * 1024 + lb);
        short8 bL = *(const short8*)(smem + H1_LO + kt * 1024 + lb);
        acc[0] = __builtin_amdgcn_mfma_f32_16x16x32_bf16(bH, wfB[0][kt], acc[0], 0, 0, 0);
        acc[0] = __builtin_amdgcn_mfma_f32_16x16x32_bf16(bL, wfB[0][kt], acc[0], 0, 0, 0);
        acc[1] = __builtin_amdgcn_mfma_f32_16x16x32_bf16(bH, wfB[1][kt], acc[1], 0, 0, 0);
        acc[1] = __builtin_amdgcn_mfma_f32_16x16x32_bf16(bL, wfB[1][kt], acc[1], 0, 0, 0);
      }
    }
    __syncthreads();  // B: MFMA LDS reads complete

    // ---- epilogue: gate-combine in-register (R5-verified mapping) ----
    float hvv[2][4];
#pragma unroll
    for (int j = 0; j < 2; ++j) {
#pragma unroll
      for (int r = 0; r < 4; ++r) {
        float a = acc[j][r] + bb[j];
        float y = 1.f / (1.f + __expf(-a * sc));
        float v = fmaf(y, sc, 1.f - sc);
        float t1 = __shfl_xor(v, 4, 64);
        float t2 = __shfl_xor(v, 8, 64);
        float t3 = __shfl_xor(t1, 8, 64);
        float pi = g1b ? (g0b ? t3 : t2) : (g0b ? t1 : v);
        float pf = g1b ? (g0b ? t2 : t3) : (g0b ? v : t1);
        float pg = g1b ? (g0b ? t1 : v) : (g0b ? t3 : t2);
        float po = g1b ? (g0b ? v : t1) : (g0b ? t2 : t3);
        float c = pf * cst[j][r] + pi * pg;
        cst[j][r] = c;
        float th = 2.f / (1.f + __expf(-2.f * c)) - 1.f;
        hvv[j][r] = po * th;
      }
    }
    // publish: lane stores m = q*4+gidx, cols (c4*2, c4*2+1) as one packed u64
    float h0s = hvv[0][0], h1s = hvv[1][0];
    if (gidx == 1) { h0s = hvv[0][1]; h1s = hvv[1][1]; }
    else if (gidx == 2) { h0s = hvv[0][2]; h1s = hvv[1][2]; }
    else if (gidx == 3) { h0s = hvv[0][3]; h1s = hvv[1][3]; }
    const unsigned pk0 = pk_enc(h0s), pk1 = pk_enc(h1s);
    const unsigned lo32 = (pk0 >> 16) | (pk1 & 0xFFFF0000u);
    const unsigned hi32 = (pk0 & 0xFFFFu) | (pk1 << 16);
    const unsigned long long val = ((unsigned long long)hi32 << 32) | lo32;
    unsigned long long* slabMy =
        ws64 + (L ? RING1 : RING0) + (size_t)((g * 8 + (t & 7)) * 4 + s) * 512;
    __hip_atomic_store(slabMy + (w * 4 + c4) * 16 + (q * 4 + gidx), val,
                       __ATOMIC_RELAXED, __HIP_MEMORY_SCOPE_AGENT);
    // self-stage into own LDS planes for next step
    {
      const int col0 = s * 64 + w * 8 + c4 * 2;
      const int kt = col0 >> 5, qq = (col0 >> 3) & 3, z = col0 & 7;
      const int off = (kt * 4 + qq) * 256 + (q * 4 + gidx) * 16 + z * 2;
      const int ph = L ? H1_HI : H0_HI, pl = L ? H1_LO : H0_LO;
      *(unsigned*)(smem + ph + off) = lo32;
      *(unsigned*)(smem + pl + off) = hi32;
    }
    // L1: out-projection partials
    if (L == 1) {
      float vr[4];
#pragma unroll
      for (int r = 0; r < 4; ++r) {
        float v = hvv[0][r] * wo2[0] + hvv[1][r] * wo2[1];
        v += __shfl_xor(v, 1, 64);
        v += __shfl_xor(v, 2, 64);
        vr[r] = v;
      }
      if ((lane & 15) == 0) {
        float4 st = make_float4(vr[0], vr[1], vr[2], vr[3]);
        *(float4*)(pout + (t & 1) * 128 + w * 16 + q * 4) = st;
      }
    }
    // release: drain this wave's stores, then per-wave sentinel
    asm volatile("s_waitcnt vmcnt(0)" ::: "memory");
    if (lane == 0)
      __hip_atomic_store(
          ws64 + (L ? SENT1 : SENT0) + (size_t)((g * 8 + (t & 7)) * 4 + s) * 8 + w,
          (unsigned long long)(t + 1), __ATOMIC_RELAXED, __HIP_MEMORY_SCOPE_AGENT);
  }
  // final out flush: h1(Sz-1) partials
  __syncthreads();
  if (L == 1 && w == 0 && lane < 16) {
    const int par = (Sz - 1) & 1;
    float sum = 0.f;
#pragma unroll
    for (int ww = 0; ww < 8; ++ww) sum += pout[par * 128 + ww * 16 + lane];
    atomicAdd(out + (size_t)(g * 16 + lane) * Sz + (Sz - 1), sum);
  }
}

extern "C" void kernel_launch(void* const* d_in, const int* in_sizes, int n_in,
                              void* d_out, int out_size, void* d_ws, size_t ws_size,
                              hipStream_t stream) {
  const float* xin   = (const float*)d_in[0];
  const float* W_in  = (const float*)d_in[1];
  const float* b_in  = (const float*)d_in[2];
  const float* W_ih0 = (const float*)d_in[3];
  const float* W_hh0 = (const float*)d_in[4];
  const float* b_ih0 = (const float*)d_in[5];
  const float* b_hh0 = (const float*)d_in[6];
  const float* W_ih1 = (const float*)d_in[7];
  const float* W_hh1 = (const float*)d_in[8];
  const float* b_ih1 = (const float*)d_in[9];
  const float* b_hh1 = (const float*)d_in[10];
  const float* W_out = (const float*)d_in[11];
  const float* b_out = (const float*)d_in[12];
  float* out = (float*)d_out;
  unsigned long long* ws64 = (unsigned long long*)d_ws;

  init_out<<<(64 * Sz + 511) / 512, 512, 0, stream>>>(b_out, out);
  lstm_v6<<<32, 512, 0, stream>>>(xin, W_in, b_in, W_ih0, W_hh0, b_ih0, b_hh0,
                                  W_ih1, W_hh1, b_ih1, b_hh1, W_out, b_out,
                                  out, ws64);
}